// Round 3
// baseline (2529.679 us; speedup 1.0000x reference)
//
#include <hip/hip_runtime.h>
#include <hip/hip_bf16.h>
#include <math.h>

// B=2 T=1024 HID=2048 H=16 D=128 DV=128 R=4 CONV=4
// Inputs fp32, output fp32 (R6-validated). Staging bf16, state fp32.
// R10: scan v5 = v4 + (a) packed-f32 d-chain math (v_pk_mul/v_pk_fma via
// float2 ext-vector), (b) permlane16/32_swap reduce tail (all-lane result,
// no readlane SALU hop; __has_builtin fallback to R9 ladder), (c) bijective
// XCD-clustered block remap (32 sharers of one (b,h) on one XCD L2).
// conv_silu vectorized x8 (ushort8). All other kernels byte-identical R9.

typedef unsigned short ushort_t;
typedef __attribute__((ext_vector_type(8))) short bf16x8;
typedef __attribute__((ext_vector_type(4))) float f32x4;
typedef __attribute__((ext_vector_type(2))) float f32x2;
typedef __attribute__((ext_vector_type(8))) unsigned short u16x8;
typedef __attribute__((ext_vector_type(2))) unsigned int u32x2;

__device__ __forceinline__ unsigned short f2bf(float f) {
  unsigned u = __float_as_uint(f);
  unsigned r = (u + 0x7FFFu + ((u >> 16) & 1u)) >> 16;  // RNE
  return (unsigned short)r;
}
__device__ __forceinline__ float bf2f(unsigned short u) {
  return __uint_as_float(((unsigned)u) << 16);
}
__device__ __forceinline__ float sigmoidf(float x) { return 1.f / (1.f + expf(-x)); }
__device__ __forceinline__ float softplusf(float x) {
  return (x > 20.f) ? x : log1pf(expf(x));
}
__device__ __forceinline__ void store1(float* p, float v) { *p = v; }
__device__ __forceinline__ void store1(unsigned short* p, float v) { *p = f2bf(v); }

// ---------------------------------------------------------------------------
// MFMA GEMM (NT): Y[m,n] = sum_k X[m,k]*W[n,k]. X:(M,K) f32, W:(N,K) f32.
// fp32 -> bf16 conversion during LDS staging. 128x128 tile, 256 thr (4 waves,
// 2x2 wave grid, 4x4 16x16 frags/wave), BK=32. LDS rows padded to 40 bf16.
// M, K multiples of 128/32; N arbitrary (guarded).
// ---------------------------------------------------------------------------
template <typename OutT>
__global__ __launch_bounds__(256) void gemm_mfma(const float* __restrict__ A,
                                                 const float* __restrict__ B,
                                                 OutT* __restrict__ Y,
                                                 int M, int N, int K) {
  __shared__ __attribute__((aligned(16))) unsigned short As[128 * 40];
  __shared__ __attribute__((aligned(16))) unsigned short Bs[128 * 40];
  const int tid = threadIdx.x;
  const int lane = tid & 63;
  const int wave = tid >> 6;
  const int quad = lane >> 4;
  const int l16 = lane & 15;
  const int wm = wave >> 1;   // 0..1
  const int wn = wave & 1;    // 0..1
  const int n0 = blockIdx.x * 128;
  const int m0 = blockIdx.y * 128;

  f32x4 acc[4][4];
#pragma unroll
  for (int i = 0; i < 4; ++i)
#pragma unroll
    for (int j = 0; j < 4; ++j) acc[i][j] = (f32x4){0.f, 0.f, 0.f, 0.f};

  for (int k0 = 0; k0 < K; k0 += 32) {
    __syncthreads();
    // stage A tile (128 x 32): 512 8-element units, 2 per thread
#pragma unroll
    for (int u = tid; u < 512; u += 256) {
      int m = u >> 2, c = u & 3;
      const float* src = A + (size_t)(m0 + m) * K + k0 + c * 8;
      float4 a0 = *(const float4*)(src);
      float4 a1 = *(const float4*)(src + 4);
      *(ushort4*)&As[m * 40 + c * 8] =
          make_ushort4(f2bf(a0.x), f2bf(a0.y), f2bf(a0.z), f2bf(a0.w));
      *(ushort4*)&As[m * 40 + c * 8 + 4] =
          make_ushort4(f2bf(a1.x), f2bf(a1.y), f2bf(a1.z), f2bf(a1.w));
    }
    // stage B tile (128 x 32), rows >= N zero-filled
#pragma unroll
    for (int u = tid; u < 512; u += 256) {
      int n = u >> 2, c = u & 3;
      float4 b0 = make_float4(0.f, 0.f, 0.f, 0.f);
      float4 b1 = b0;
      if (n0 + n < N) {
        const float* src = B + (size_t)(n0 + n) * K + k0 + c * 8;
        b0 = *(const float4*)(src);
        b1 = *(const float4*)(src + 4);
      }
      *(ushort4*)&Bs[n * 40 + c * 8] =
          make_ushort4(f2bf(b0.x), f2bf(b0.y), f2bf(b0.z), f2bf(b0.w));
      *(ushort4*)&Bs[n * 40 + c * 8 + 4] =
          make_ushort4(f2bf(b1.x), f2bf(b1.y), f2bf(b1.z), f2bf(b1.w));
    }
    __syncthreads();

    bf16x8 av[4], bv[4];
#pragma unroll
    for (int i = 0; i < 4; ++i)
      av[i] = *(const bf16x8*)&As[(wm * 64 + i * 16 + l16) * 40 + quad * 8];
#pragma unroll
    for (int j = 0; j < 4; ++j)
      bv[j] = *(const bf16x8*)&Bs[(wn * 64 + j * 16 + l16) * 40 + quad * 8];
#pragma unroll
    for (int i = 0; i < 4; ++i)
#pragma unroll
      for (int j = 0; j < 4; ++j)
        acc[i][j] = __builtin_amdgcn_mfma_f32_16x16x32_bf16(av[i], bv[j], acc[i][j], 0, 0, 0);
  }

  // epilogue: D[row=quad*4+reg][col=l16] per 16x16 tile
#pragma unroll
  for (int i = 0; i < 4; ++i)
#pragma unroll
    for (int j = 0; j < 4; ++j) {
      int rr = m0 + wm * 64 + i * 16 + quad * 4;
      int cc = n0 + wn * 64 + j * 16 + l16;
      if (cc < N) {
#pragma unroll
        for (int r = 0; r < 4; ++r)
          store1(Y + (size_t)(rr + r) * N + cc, acc[i][j][r]);
      }
    }
}

// ---------------------------------------------------------------------------
// Depthwise causal conv (K=4) + silu — vectorized x8 (ushort8 loads/stores).
// C multiple of 8 so all 8 elements share (m, t); zeroed vectors make the
// causal guards value-identical to the scalar R6-validated version.
// ---------------------------------------------------------------------------
__global__ __launch_bounds__(256) void conv_silu_v8(const unsigned short* __restrict__ X,
                                                    const float* __restrict__ Wc,
                                                    unsigned short* __restrict__ Y,
                                                    int C, int total8) {
  int i8 = blockIdx.x * 256 + threadIdx.x;
  if (i8 >= total8) return;
  int idx = i8 * 8;
  int c = idx % C;
  int m = idx / C;
  int t = m & 1023;
  u16x8 x0 = *(const u16x8*)(X + idx);
  u16x8 x1 = (u16x8)(unsigned short)0;
  u16x8 x2 = x1, x3 = x1;
  if (t >= 1) x1 = *(const u16x8*)(X + idx - C);
  if (t >= 2) x2 = *(const u16x8*)(X + idx - 2 * C);
  if (t >= 3) x3 = *(const u16x8*)(X + idx - 3 * C);
  u16x8 out;
#pragma unroll
  for (int e = 0; e < 8; ++e) {
    float4 w4 = *(const float4*)(Wc + (size_t)(c + e) * 4);
    float acc = w4.w * bf2f(x0[e]);
    acc = fmaf(w4.z, bf2f(x1[e]), acc);
    acc = fmaf(w4.y, bf2f(x2[e]), acc);
    acc = fmaf(w4.x, bf2f(x3[e]), acc);
    out[e] = f2bf(acc * sigmoidf(acc));
  }
  *(u16x8*)(Y + idx) = out;
}

// ---------------------------------------------------------------------------
// l2norm rows of 128 (bf16, in-place) — R6-validated.
// ---------------------------------------------------------------------------
__global__ __launch_bounds__(256) void l2norm_bf16(unsigned short* __restrict__ X,
                                                   int rows, float post) {
  int row = blockIdx.x * 4 + (threadIdx.x >> 6);
  int lane = threadIdx.x & 63;
  if (row >= rows) return;
  unsigned short* p = X + (size_t)row * 128;
  float a = bf2f(p[lane]), b = bf2f(p[lane + 64]);
  float ss = fmaf(a, a, b * b);
#pragma unroll
  for (int m = 32; m; m >>= 1) ss += __shfl_xor(ss, m);
  float sc = rsqrtf(ss + 1e-6f) * post;
  p[lane] = f2bf(a * sc);
  p[lane + 64] = f2bf(b * sc);
}

// ---------------------------------------------------------------------------
// decay in-place (R6-validated).
// ---------------------------------------------------------------------------
__global__ __launch_bounds__(256) void decay_ip(float* __restrict__ G,
                                                const float* __restrict__ alog,
                                                const float* __restrict__ dtb,
                                                int total) {
  int idx = blockIdx.x * 256 + threadIdx.x;
  if (idx >= total) return;
  int n = idx & 2047;
  float A = expf(alog[n >> 7]);
  float x = G[idx] + dtb[n];
  G[idx] = expf(-A * softplusf(x));
}

__global__ __launch_bounds__(256) void sigmoid_ip(float* __restrict__ G, int total) {
  int idx = blockIdx.x * 256 + threadIdx.x;
  if (idx < total) G[idx] = sigmoidf(G[idx]);
}

// ---------------------------------------------------------------------------
// Recurrent scan v5 — 1 column per wave, 64 lanes over d=128 (2 d per lane),
// packed-f32 math on (d0,d0+1) pairs, permlane-swap reduce tail, XCD-
// clustered block remap. 1024 blocks x 256 threads; 4096 waves = 4/SIMD.
// red64: 4 validated DPP stages (xor1 0xB1, xor2 0x4E, half_mirror 0x141,
// mirror 0x140 -> all 16 lanes hold row sum), then permlane16_swap-add
// (x[l]+=x[l^16]) and permlane32_swap-add (x[l]+=x[l^32]) — with equal
// operands the two outputs always hold {x[l], x[l^k]} in some order, so
// their sum is role-agnostic. All lanes end with the 64-lane total.
// ---------------------------------------------------------------------------
template <int CTRL>
__device__ __forceinline__ float dppadd(float x) {
  int y = __builtin_amdgcn_update_dpp(0, __float_as_int(x), CTRL, 0xF, 0xF, true);
  return x + __int_as_float(y);
}
#if __has_builtin(__builtin_amdgcn_permlane16_swap) && __has_builtin(__builtin_amdgcn_permlane32_swap)
__device__ __forceinline__ float red64(float x) {
  x = dppadd<0xB1>(x);
  x = dppadd<0x4E>(x);
  x = dppadd<0x141>(x);
  x = dppadd<0x140>(x);
  u32x2 p16 = __builtin_amdgcn_permlane16_swap(__float_as_uint(x), __float_as_uint(x), false, false);
  x = __uint_as_float(p16.x) + __uint_as_float(p16.y);
  u32x2 p32 = __builtin_amdgcn_permlane32_swap(__float_as_uint(x), __float_as_uint(x), false, false);
  x = __uint_as_float(p32.x) + __uint_as_float(p32.y);
  return x;
}
#else
// R9-validated fallback: bcast15/31 + readlane broadcast.
__device__ __forceinline__ float red64(float x) {
  x = dppadd<0xB1>(x);
  x = dppadd<0x4E>(x);
  x = dppadd<0x141>(x);
  x = dppadd<0x140>(x);
  x = dppadd<0x142>(x);
  x = dppadd<0x143>(x);
  return __int_as_float(__builtin_amdgcn_readlane(__float_as_int(x), 63));
}
#endif

struct Pref {
  ushort2 k[4];        // k[j] at d0, d0+1
  ushort2 q;
  float2 d;
  float4 beta;
  unsigned short v[4]; // v[j] at column col (wave-uniform)
};

__global__ __launch_bounds__(256) void scan_kernel5(
    const unsigned short* __restrict__ Qn, const unsigned short* __restrict__ Kn,
    const unsigned short* __restrict__ Vb, const float* __restrict__ Dec,
    const float* __restrict__ BetaS, const float* __restrict__ ml,
    const float* __restrict__ alog, const float* __restrict__ dtb,
    float* __restrict__ O) {
  // Bijective XCD-clustering: all 32 cq-blocks of one (b,h) share orig%8,
  // i.e. land on one XCD's L2 (dispatch round-robins on original index).
  const int orig = blockIdx.x;       // 0..1023
  const int xcd = orig & 7;
  const int rr = orig >> 3;          // 0..127
  const int bh = xcd * 4 + (rr & 3); // 0..31
  const int cq = rr >> 2;            // 0..31
  const int h = bh & 15;
  const int b = bh >> 4;
  const int wave = threadIdx.x >> 6; // 0..3 -> column within group
  const int lane = threadIdx.x & 63;
  const int col = cq * 4 + wave;
  const int d0 = lane * 2;

  const float A = expf(alog[h]);
  f32x2 dfill2;
  dfill2.x = expf(-A * softplusf(-10000.f + dtb[h * 128 + d0]));
  dfill2.y = expf(-A * softplusf(-10000.f + dtb[h * 128 + d0 + 1]));

  float wj[4];
  {
    float l0 = ml[h * 4 + 0], l1 = ml[h * 4 + 1];
    float l2 = ml[h * 4 + 2], l3 = ml[h * 4 + 3];
    float mx = fmaxf(fmaxf(l0, l1), fmaxf(l2, l3));
    float e0 = expf(l0 - mx), e1 = expf(l1 - mx);
    float e2 = expf(l2 - mx), e3 = expf(l3 - mx);
    float inv = 1.f / (e0 + e1 + e2 + e3);
    wj[0] = e0 * inv; wj[1] = e1 * inv; wj[2] = e2 * inv; wj[3] = e3 * inv;
  }

  f32x2 S = (f32x2){0.f, 0.f};

  auto LD = [&](int t, Pref& P) {
    const size_t base = ((size_t)(b * 1024 + t) * 16 + h);
    const unsigned short* kp = Kn + base * 512 + d0;
    const unsigned short* vp = Vb + base * 512 + col;
#pragma unroll
    for (int j = 0; j < 4; ++j) {
      P.k[j] = *(const ushort2*)(kp + j * 128);
      P.v[j] = vp[j * 128];
    }
    P.q = *(const ushort2*)(Qn + base * 128 + d0);
    P.d = *(const float2*)(Dec + base * 128 + d0);
    P.beta = *(const float4*)(BetaS + base * 4);
  };

  auto STEP = [&](const Pref& P, int t) {
    f32x2 qf;
    qf.x = bf2f(P.q.x);
    qf.y = bf2f(P.q.y);
    f32x2 o2 = (f32x2){0.f, 0.f};
    const float bc[4] = {P.beta.x, P.beta.y, P.beta.z, P.beta.w};
#pragma unroll
    for (int j = 0; j < 4; ++j) {
      f32x2 kf;
      kf.x = bf2f(P.k[j].x);
      kf.y = bf2f(P.k[j].y);
      f32x2 dd;
      if (j == 0) { dd.x = P.d.x; dd.y = P.d.y; } else { dd = dfill2; }
      S = S * dd;                                   // v_pk_mul_f32
      f32x2 tp = kf * S;                            // v_pk_mul_f32
      float u = red64(tp.x + tp.y);
      float cc = bc[j] * (bf2f(P.v[j]) - u);
      f32x2 cc2 = (f32x2){cc, cc};
      S = __builtin_elementwise_fma(cc2, kf, S);    // v_pk_fma_f32
      f32x2 tq = qf * S;                            // v_pk_mul_f32
      f32x2 w2 = (f32x2){wj[j], wj[j]};
      o2 = __builtin_elementwise_fma(w2, tq, o2);   // v_pk_fma_f32
    }
    float o_acc = red64(o2.x + o2.y);
    if (lane == 0) {
      const size_t base = ((size_t)(b * 1024 + t) * 16 + h);
      O[base * 128 + col] = o_acc;
    }
  };

  Pref P0, P1;
  LD(0, P0);
  for (int t = 0; t < 1024; t += 2) {
    LD(t + 1, P1);
    STEP(P0, t);
    if (t + 2 < 1024) LD(t + 2, P0);
    STEP(P1, t + 1);
  }
}

// ---------------------------------------------------------------------------
// RMS-norm * o_norm_w * sigmoid(gate + g2_b), in-place on O(f32) — R6-validated.
// ---------------------------------------------------------------------------
__global__ __launch_bounds__(256) void norm_gate(float* __restrict__ O,
                                                 const unsigned short* __restrict__ G,
                                                 const float* __restrict__ g2b,
                                                 const float* __restrict__ onw,
                                                 int rows) {
  int row = blockIdx.x * 4 + (threadIdx.x >> 6);
  int lane = threadIdx.x & 63;
  if (row >= rows) return;
  float* p = O + (size_t)row * 128;
  int m = row >> 4, h = row & 15;
  const unsigned short* gp = G + (size_t)m * 2048 + h * 128;
  const float* gb = g2b + h * 128;
  float a = p[lane], bv = p[lane + 64];
  float ss = fmaf(a, a, bv * bv);
#pragma unroll
  for (int k = 32; k; k >>= 1) ss += __shfl_xor(ss, k);
  float sc = rsqrtf(ss * (1.f / 128.f) + 1e-5f);
  float ga = sigmoidf(bf2f(gp[lane]) + gb[lane]);
  float gbv = sigmoidf(bf2f(gp[lane + 64]) + gb[lane + 64]);
  p[lane] = a * sc * onw[lane] * ga;
  p[lane + 64] = bv * sc * onw[lane + 64] * gbv;
}

// ---------------------------------------------------------------------------
extern "C" void kernel_launch(void* const* d_in, const int* in_sizes, int n_in,
                              void* d_out, int out_size, void* d_ws, size_t ws_size,
                              hipStream_t stream) {
  const float* x    = (const float*)d_in[0];
  const float* qw   = (const float*)d_in[1];
  const float* kw   = (const float*)d_in[2];
  const float* vw   = (const float*)d_in[3];
  const float* qcw  = (const float*)d_in[4];
  const float* kcw  = (const float*)d_in[5];
  const float* vcw  = (const float*)d_in[6];
  const float* f1w  = (const float*)d_in[7];
  const float* f2w  = (const float*)d_in[8];
  const float* bw   = (const float*)d_in[9];
  const float* ml   = (const float*)d_in[10];
  const float* alog = (const float*)d_in[11];
  const float* dtb  = (const float*)d_in[12];
  const float* g1w  = (const float*)d_in[13];
  const float* g2w  = (const float*)d_in[14];
  const float* g2b  = (const float*)d_in[15];
  const float* onw  = (const float*)d_in[16];
  const float* ow   = (const float*)d_in[17];
  float* out = (float*)d_out;  // fp32 output

  // workspace carve — peak 120 MiB (R6-validated layout).
  char* w8 = (char*)d_ws;
  unsigned short* P    = (unsigned short*)(w8);               // [0, 32M) staging
  float*          dec  = (float*)(w8);                        // [0, 16M)
  unsigned short* gate = (unsigned short*)(w8 + 16777216);    // 8 MB
  float*          beta = (float*)(w8 + 25165824);             // 512 KB
  float*          g1t  = (float*)(w8 + 25690112);             // 1 MB
  unsigned short* Kc   = (unsigned short*)(w8 + 33554432);    // 32 MB
  unsigned short* Vc   = (unsigned short*)(w8 + 67108864);    // 32 MB
  unsigned short* Qc   = (unsigned short*)(w8 + 100663296);   // 8 MB
  float*          o    = (float*)(w8 + 109051904);            // 16 MB (ends 120 MiB)
  (void)ws_size;

  const int M = 2048;
  dim3 blk(256);

  // ---- phase 1: projections (MFMA) + conv ----
  gemm_mfma<unsigned short><<<dim3(64, 16), blk, 0, stream>>>(x, kw, P, M, 8192, 2048);
  conv_silu_v8<<<8192, blk, 0, stream>>>(P, kcw, Kc, 8192, 2097152);
  gemm_mfma<unsigned short><<<dim3(64, 16), blk, 0, stream>>>(x, vw, P, M, 8192, 2048);
  conv_silu_v8<<<8192, blk, 0, stream>>>(P, vcw, Vc, 8192, 2097152);
  gemm_mfma<unsigned short><<<dim3(16, 16), blk, 0, stream>>>(x, qw, P, M, 2048, 2048);
  conv_silu_v8<<<2048, blk, 0, stream>>>(P, qcw, Qc, 2048, 524288);

  // ---- phase 2: small projections (P region now dead) ----
  gemm_mfma<float><<<dim3(1, 16), blk, 0, stream>>>(x, f1w, g1t, M, 128, 2048);
  gemm_mfma<float><<<dim3(16, 16), blk, 0, stream>>>(g1t, f2w, dec, M, 2048, 128);
  decay_ip<<<16384, blk, 0, stream>>>(dec, alog, dtb, 4194304);

  gemm_mfma<float><<<dim3(1, 16), blk, 0, stream>>>(x, bw, beta, M, 64, 2048);
  sigmoid_ip<<<512, blk, 0, stream>>>(beta, 131072);

  gemm_mfma<float><<<dim3(1, 16), blk, 0, stream>>>(x, g1w, g1t, M, 128, 2048);
  gemm_mfma<unsigned short><<<dim3(16, 16), blk, 0, stream>>>(g1t, g2w, gate, M, 2048, 128);

  // ---- l2 norms (in-place bf16) ----
  l2norm_bf16<<<8192, blk, 0, stream>>>(Qc, 32768, 0.08838834764831845f);
  l2norm_bf16<<<32768, blk, 0, stream>>>(Kc, 131072, 1.0f);

  // ---- recurrent scan (pk-math, permlane reduce, XCD-clustered) ----
  scan_kernel5<<<1024, dim3(256), 0, stream>>>(Qc, Kc, Vc, dec, beta, ml, alog, dtb, o);

  // ---- RMS-norm + gate ----
  norm_gate<<<8192, blk, 0, stream>>>(o, gate, g2b, onw, 32768);

  // ---- final projection -> fp32 out ----
  gemm_mfma<float><<<dim3(16, 16), blk, 0, stream>>>(o, ow, out, M, 2048, 2048);
}

// Round 4
// 2055.461 us; speedup vs baseline: 1.2307x; 1.2307x over previous
//
#include <hip/hip_runtime.h>
#include <hip/hip_bf16.h>
#include <math.h>

// B=2 T=1024 HID=2048 H=16 D=128 DV=128 R=4 CONV=4
// Inputs fp32, output fp32 (R6-validated). Staging bf16, state fp32.
// R11: scan v6 = R9-validated scalar math + 6-stage DPP ladder (readlane
// broadcast for u; lane-63 store for o) + XCD-clustered remap (R10-verified
// FETCH 364GB->91GB). pk-f32/permlane experiment reverted (R10: +28% VALU).
// v_cvt_pk_bf16_f32 (HW RNE, 1 instr / 2 elems) replaces 3-op manual f2bf
// in GEMM staging, GEMM bf16 epilogue, conv output.

typedef unsigned short ushort_t;
typedef __attribute__((ext_vector_type(8))) short bf16x8;
typedef __attribute__((ext_vector_type(4))) float f32x4;
typedef __attribute__((ext_vector_type(8))) unsigned short u16x8;

__device__ __forceinline__ unsigned short f2bf(float f) {
  unsigned u = __float_as_uint(f);
  unsigned r = (u + 0x7FFFu + ((u >> 16) & 1u)) >> 16;  // RNE
  return (unsigned short)r;
}
// HW packed fp32->bf16 (RNE), lo in [15:0], hi in [31:16]. Guide T12 recipe.
__device__ __forceinline__ unsigned f2bf_pk(float lo, float hi) {
  unsigned r;
  asm("v_cvt_pk_bf16_f32 %0, %1, %2" : "=v"(r) : "v"(lo), "v"(hi));
  return r;
}
__device__ __forceinline__ float bf2f(unsigned short u) {
  return __uint_as_float(((unsigned)u) << 16);
}
__device__ __forceinline__ float sigmoidf(float x) { return 1.f / (1.f + expf(-x)); }
__device__ __forceinline__ float softplusf(float x) {
  return (x > 20.f) ? x : log1pf(expf(x));
}
__device__ __forceinline__ void store1(float* p, float v) { *p = v; }
__device__ __forceinline__ void store1(unsigned short* p, float v) {
  *p = (unsigned short)f2bf_pk(v, v);
}

// ---------------------------------------------------------------------------
// MFMA GEMM (NT): Y[m,n] = sum_k X[m,k]*W[n,k]. X:(M,K) f32, W:(N,K) f32.
// fp32 -> bf16 conversion during LDS staging via v_cvt_pk_bf16_f32.
// 128x128 tile, 256 thr (4 waves, 2x2 wave grid, 4x4 16x16 frags/wave),
// BK=32. LDS rows padded to 40 bf16. M, K multiples of 128/32; N guarded.
// ---------------------------------------------------------------------------
template <typename OutT>
__global__ __launch_bounds__(256) void gemm_mfma(const float* __restrict__ A,
                                                 const float* __restrict__ B,
                                                 OutT* __restrict__ Y,
                                                 int M, int N, int K) {
  __shared__ __attribute__((aligned(16))) unsigned short As[128 * 40];
  __shared__ __attribute__((aligned(16))) unsigned short Bs[128 * 40];
  const int tid = threadIdx.x;
  const int lane = tid & 63;
  const int wave = tid >> 6;
  const int quad = lane >> 4;
  const int l16 = lane & 15;
  const int wm = wave >> 1;   // 0..1
  const int wn = wave & 1;    // 0..1
  const int n0 = blockIdx.x * 128;
  const int m0 = blockIdx.y * 128;

  f32x4 acc[4][4];
#pragma unroll
  for (int i = 0; i < 4; ++i)
#pragma unroll
    for (int j = 0; j < 4; ++j) acc[i][j] = (f32x4){0.f, 0.f, 0.f, 0.f};

  for (int k0 = 0; k0 < K; k0 += 32) {
    __syncthreads();
    // stage A tile (128 x 32): 512 8-element units, 2 per thread
#pragma unroll
    for (int u = tid; u < 512; u += 256) {
      int m = u >> 2, c = u & 3;
      const float* src = A + (size_t)(m0 + m) * K + k0 + c * 8;
      float4 a0 = *(const float4*)(src);
      float4 a1 = *(const float4*)(src + 4);
      *(uint2*)&As[m * 40 + c * 8] =
          make_uint2(f2bf_pk(a0.x, a0.y), f2bf_pk(a0.z, a0.w));
      *(uint2*)&As[m * 40 + c * 8 + 4] =
          make_uint2(f2bf_pk(a1.x, a1.y), f2bf_pk(a1.z, a1.w));
    }
    // stage B tile (128 x 32), rows >= N zero-filled
#pragma unroll
    for (int u = tid; u < 512; u += 256) {
      int n = u >> 2, c = u & 3;
      float4 b0 = make_float4(0.f, 0.f, 0.f, 0.f);
      float4 b1 = b0;
      if (n0 + n < N) {
        const float* src = B + (size_t)(n0 + n) * K + k0 + c * 8;
        b0 = *(const float4*)(src);
        b1 = *(const float4*)(src + 4);
      }
      *(uint2*)&Bs[n * 40 + c * 8] =
          make_uint2(f2bf_pk(b0.x, b0.y), f2bf_pk(b0.z, b0.w));
      *(uint2*)&Bs[n * 40 + c * 8 + 4] =
          make_uint2(f2bf_pk(b1.x, b1.y), f2bf_pk(b1.z, b1.w));
    }
    __syncthreads();

    bf16x8 av[4], bv[4];
#pragma unroll
    for (int i = 0; i < 4; ++i)
      av[i] = *(const bf16x8*)&As[(wm * 64 + i * 16 + l16) * 40 + quad * 8];
#pragma unroll
    for (int j = 0; j < 4; ++j)
      bv[j] = *(const bf16x8*)&Bs[(wn * 64 + j * 16 + l16) * 40 + quad * 8];
#pragma unroll
    for (int i = 0; i < 4; ++i)
#pragma unroll
      for (int j = 0; j < 4; ++j)
        acc[i][j] = __builtin_amdgcn_mfma_f32_16x16x32_bf16(av[i], bv[j], acc[i][j], 0, 0, 0);
  }

  // epilogue: D[row=quad*4+reg][col=l16] per 16x16 tile
#pragma unroll
  for (int i = 0; i < 4; ++i)
#pragma unroll
    for (int j = 0; j < 4; ++j) {
      int rr = m0 + wm * 64 + i * 16 + quad * 4;
      int cc = n0 + wn * 64 + j * 16 + l16;
      if (cc < N) {
#pragma unroll
        for (int r = 0; r < 4; ++r)
          store1(Y + (size_t)(rr + r) * N + cc, acc[i][j][r]);
      }
    }
}

// ---------------------------------------------------------------------------
// Depthwise causal conv (K=4) + silu — vectorized x8 (ushort8), cvt_pk out.
// ---------------------------------------------------------------------------
__global__ __launch_bounds__(256) void conv_silu_v8(const unsigned short* __restrict__ X,
                                                    const float* __restrict__ Wc,
                                                    unsigned short* __restrict__ Y,
                                                    int C, int total8) {
  int i8 = blockIdx.x * 256 + threadIdx.x;
  if (i8 >= total8) return;
  int idx = i8 * 8;
  int c = idx % C;
  int m = idx / C;
  int t = m & 1023;
  u16x8 x0 = *(const u16x8*)(X + idx);
  u16x8 x1 = (u16x8)(unsigned short)0;
  u16x8 x2 = x1, x3 = x1;
  if (t >= 1) x1 = *(const u16x8*)(X + idx - C);
  if (t >= 2) x2 = *(const u16x8*)(X + idx - 2 * C);
  if (t >= 3) x3 = *(const u16x8*)(X + idx - 3 * C);
  float r[8];
#pragma unroll
  for (int e = 0; e < 8; ++e) {
    float4 w4 = *(const float4*)(Wc + (size_t)(c + e) * 4);
    float acc = w4.w * bf2f(x0[e]);
    acc = fmaf(w4.z, bf2f(x1[e]), acc);
    acc = fmaf(w4.y, bf2f(x2[e]), acc);
    acc = fmaf(w4.x, bf2f(x3[e]), acc);
    r[e] = acc * sigmoidf(acc);
  }
  *(uint4*)(Y + idx) = make_uint4(f2bf_pk(r[0], r[1]), f2bf_pk(r[2], r[3]),
                                  f2bf_pk(r[4], r[5]), f2bf_pk(r[6], r[7]));
}

// ---------------------------------------------------------------------------
// l2norm rows of 128 (bf16, in-place) — R6-validated.
// ---------------------------------------------------------------------------
__global__ __launch_bounds__(256) void l2norm_bf16(unsigned short* __restrict__ X,
                                                   int rows, float post) {
  int row = blockIdx.x * 4 + (threadIdx.x >> 6);
  int lane = threadIdx.x & 63;
  if (row >= rows) return;
  unsigned short* p = X + (size_t)row * 128;
  float a = bf2f(p[lane]), b = bf2f(p[lane + 64]);
  float ss = fmaf(a, a, b * b);
#pragma unroll
  for (int m = 32; m; m >>= 1) ss += __shfl_xor(ss, m);
  float sc = rsqrtf(ss + 1e-6f) * post;
  p[lane] = f2bf(a * sc);
  p[lane + 64] = f2bf(b * sc);
}

// ---------------------------------------------------------------------------
// decay in-place (R6-validated).
// ---------------------------------------------------------------------------
__global__ __launch_bounds__(256) void decay_ip(float* __restrict__ G,
                                                const float* __restrict__ alog,
                                                const float* __restrict__ dtb,
                                                int total) {
  int idx = blockIdx.x * 256 + threadIdx.x;
  if (idx >= total) return;
  int n = idx & 2047;
  float A = expf(alog[n >> 7]);
  float x = G[idx] + dtb[n];
  G[idx] = expf(-A * softplusf(x));
}

__global__ __launch_bounds__(256) void sigmoid_ip(float* __restrict__ G, int total) {
  int idx = blockIdx.x * 256 + threadIdx.x;
  if (idx < total) G[idx] = sigmoidf(G[idx]);
}

// ---------------------------------------------------------------------------
// Recurrent scan v6 — R9-validated structure: 1 column/wave, 64 lanes over
// d=128 (2 d/lane), scalar math, all-DPP reduce ladder:
//   xor1(0xB1), xor2(0x4E), half_mirror(0x141), mirror(0x140) -> 16-lane row
//   sums; row_bcast15(0x142), row_bcast31(0x143) -> lane 63 = 64-lane total.
// u-reduce broadcasts via v_readlane(63); o-reduce stores from lane 63
// directly (no readlane — total already there).
// XCD-clustered bijective remap (R10-verified: FETCH = unique bytes).
// ---------------------------------------------------------------------------
template <int CTRL>
__device__ __forceinline__ float dppadd(float x) {
  int y = __builtin_amdgcn_update_dpp(0, __float_as_int(x), CTRL, 0xF, 0xF, true);
  return x + __int_as_float(y);
}
__device__ __forceinline__ float red64_l63(float x) {
  x = dppadd<0xB1>(x);
  x = dppadd<0x4E>(x);
  x = dppadd<0x141>(x);
  x = dppadd<0x140>(x);
  x = dppadd<0x142>(x);
  x = dppadd<0x143>(x);
  return x;  // lane 63 holds the 64-lane total
}
__device__ __forceinline__ float red64(float x) {
  return __int_as_float(__builtin_amdgcn_readlane(__float_as_int(red64_l63(x)), 63));
}

struct Pref {
  ushort2 k[4];        // k[j] at d0, d0+1
  ushort2 q;
  float2 d;
  float4 beta;
  unsigned short v[4]; // v[j] at column col (wave-uniform)
};

__global__ __launch_bounds__(256) void scan_kernel6(
    const unsigned short* __restrict__ Qn, const unsigned short* __restrict__ Kn,
    const unsigned short* __restrict__ Vb, const float* __restrict__ Dec,
    const float* __restrict__ BetaS, const float* __restrict__ ml,
    const float* __restrict__ alog, const float* __restrict__ dtb,
    float* __restrict__ O) {
  // Bijective XCD-clustering: all 32 cq-blocks of one (b,h) share orig%8,
  // i.e. land on one XCD's L2 (dispatch round-robins on original index).
  const int orig = blockIdx.x;       // 0..1023
  const int xcd = orig & 7;
  const int rr = orig >> 3;          // 0..127
  const int bh = xcd * 4 + (rr & 3); // 0..31
  const int cq = rr >> 2;            // 0..31
  const int h = bh & 15;
  const int b = bh >> 4;
  const int wave = threadIdx.x >> 6; // 0..3 -> column within group
  const int lane = threadIdx.x & 63;
  const int col = cq * 4 + wave;
  const int d0 = lane * 2;

  const float A = expf(alog[h]);
  const float df0 = expf(-A * softplusf(-10000.f + dtb[h * 128 + d0]));
  const float df1 = expf(-A * softplusf(-10000.f + dtb[h * 128 + d0 + 1]));

  float wj[4];
  {
    float l0 = ml[h * 4 + 0], l1 = ml[h * 4 + 1];
    float l2 = ml[h * 4 + 2], l3 = ml[h * 4 + 3];
    float mx = fmaxf(fmaxf(l0, l1), fmaxf(l2, l3));
    float e0 = expf(l0 - mx), e1 = expf(l1 - mx);
    float e2 = expf(l2 - mx), e3 = expf(l3 - mx);
    float inv = 1.f / (e0 + e1 + e2 + e3);
    wj[0] = e0 * inv; wj[1] = e1 * inv; wj[2] = e2 * inv; wj[3] = e3 * inv;
  }

  float S0 = 0.f, S1 = 0.f;

  auto LD = [&](int t, Pref& P) {
    const size_t base = ((size_t)(b * 1024 + t) * 16 + h);
    const unsigned short* kp = Kn + base * 512 + d0;
    const unsigned short* vp = Vb + base * 512 + col;
#pragma unroll
    for (int j = 0; j < 4; ++j) {
      P.k[j] = *(const ushort2*)(kp + j * 128);
      P.v[j] = vp[j * 128];
    }
    P.q = *(const ushort2*)(Qn + base * 128 + d0);
    P.d = *(const float2*)(Dec + base * 128 + d0);
    P.beta = *(const float4*)(BetaS + base * 4);
  };

  auto STEP = [&](const Pref& P, int t) {
    const float qf0 = bf2f(P.q.x), qf1 = bf2f(P.q.y);
    float o_acc = 0.f;
    const float bc[4] = {P.beta.x, P.beta.y, P.beta.z, P.beta.w};
#pragma unroll
    for (int j = 0; j < 4; ++j) {
      const float kf0 = bf2f(P.k[j].x), kf1 = bf2f(P.k[j].y);
      const float dd0 = (j == 0) ? P.d.x : df0;
      const float dd1 = (j == 0) ? P.d.y : df1;
      S0 *= dd0;
      S1 *= dd1;
      float u = red64(fmaf(kf0, S0, kf1 * S1));
      float cc = bc[j] * (bf2f(P.v[j]) - u);
      S0 = fmaf(cc, kf0, S0);
      S1 = fmaf(cc, kf1, S1);
      o_acc = fmaf(wj[j], fmaf(qf0, S0, qf1 * S1), o_acc);
    }
    o_acc = red64_l63(o_acc);
    if (lane == 63) {
      const size_t base = ((size_t)(b * 1024 + t) * 16 + h);
      O[base * 128 + col] = o_acc;
    }
  };

  Pref P0, P1;
  LD(0, P0);
  for (int t = 0; t < 1024; t += 2) {
    LD(t + 1, P1);
    STEP(P0, t);
    if (t + 2 < 1024) LD(t + 2, P0);
    STEP(P1, t + 1);
  }
}

// ---------------------------------------------------------------------------
// RMS-norm * o_norm_w * sigmoid(gate + g2_b), in-place on O(f32) — R6-validated.
// ---------------------------------------------------------------------------
__global__ __launch_bounds__(256) void norm_gate(float* __restrict__ O,
                                                 const unsigned short* __restrict__ G,
                                                 const float* __restrict__ g2b,
                                                 const float* __restrict__ onw,
                                                 int rows) {
  int row = blockIdx.x * 4 + (threadIdx.x >> 6);
  int lane = threadIdx.x & 63;
  if (row >= rows) return;
  float* p = O + (size_t)row * 128;
  int m = row >> 4, h = row & 15;
  const unsigned short* gp = G + (size_t)m * 2048 + h * 128;
  const float* gb = g2b + h * 128;
  float a = p[lane], bv = p[lane + 64];
  float ss = fmaf(a, a, bv * bv);
#pragma unroll
  for (int k = 32; k; k >>= 1) ss += __shfl_xor(ss, k);
  float sc = rsqrtf(ss * (1.f / 128.f) + 1e-5f);
  float ga = sigmoidf(bf2f(gp[lane]) + gb[lane]);
  float gbv = sigmoidf(bf2f(gp[lane + 64]) + gb[lane + 64]);
  p[lane] = a * sc * onw[lane] * ga;
  p[lane + 64] = bv * sc * onw[lane + 64] * gbv;
}

// ---------------------------------------------------------------------------
extern "C" void kernel_launch(void* const* d_in, const int* in_sizes, int n_in,
                              void* d_out, int out_size, void* d_ws, size_t ws_size,
                              hipStream_t stream) {
  const float* x    = (const float*)d_in[0];
  const float* qw   = (const float*)d_in[1];
  const float* kw   = (const float*)d_in[2];
  const float* vw   = (const float*)d_in[3];
  const float* qcw  = (const float*)d_in[4];
  const float* kcw  = (const float*)d_in[5];
  const float* vcw  = (const float*)d_in[6];
  const float* f1w  = (const float*)d_in[7];
  const float* f2w  = (const float*)d_in[8];
  const float* bw   = (const float*)d_in[9];
  const float* ml   = (const float*)d_in[10];
  const float* alog = (const float*)d_in[11];
  const float* dtb  = (const float*)d_in[12];
  const float* g1w  = (const float*)d_in[13];
  const float* g2w  = (const float*)d_in[14];
  const float* g2b  = (const float*)d_in[15];
  const float* onw  = (const float*)d_in[16];
  const float* ow   = (const float*)d_in[17];
  float* out = (float*)d_out;  // fp32 output

  // workspace carve — peak 120 MiB (R6-validated layout).
  char* w8 = (char*)d_ws;
  unsigned short* P    = (unsigned short*)(w8);               // [0, 32M) staging
  float*          dec  = (float*)(w8);                        // [0, 16M)
  unsigned short* gate = (unsigned short*)(w8 + 16777216);    // 8 MB
  float*          beta = (float*)(w8 + 25165824);             // 512 KB
  float*          g1t  = (float*)(w8 + 25690112);             // 1 MB
  unsigned short* Kc   = (unsigned short*)(w8 + 33554432);    // 32 MB
  unsigned short* Vc   = (unsigned short*)(w8 + 67108864);    // 32 MB
  unsigned short* Qc   = (unsigned short*)(w8 + 100663296);   // 8 MB
  float*          o    = (float*)(w8 + 109051904);            // 16 MB (ends 120 MiB)
  (void)ws_size;

  const int M = 2048;
  dim3 blk(256);

  // ---- phase 1: projections (MFMA) + conv ----
  gemm_mfma<unsigned short><<<dim3(64, 16), blk, 0, stream>>>(x, kw, P, M, 8192, 2048);
  conv_silu_v8<<<8192, blk, 0, stream>>>(P, kcw, Kc, 8192, 2097152);
  gemm_mfma<unsigned short><<<dim3(64, 16), blk, 0, stream>>>(x, vw, P, M, 8192, 2048);
  conv_silu_v8<<<8192, blk, 0, stream>>>(P, vcw, Vc, 8192, 2097152);
  gemm_mfma<unsigned short><<<dim3(16, 16), blk, 0, stream>>>(x, qw, P, M, 2048, 2048);
  conv_silu_v8<<<2048, blk, 0, stream>>>(P, qcw, Qc, 2048, 524288);

  // ---- phase 2: small projections (P region now dead) ----
  gemm_mfma<float><<<dim3(1, 16), blk, 0, stream>>>(x, f1w, g1t, M, 128, 2048);
  gemm_mfma<float><<<dim3(16, 16), blk, 0, stream>>>(g1t, f2w, dec, M, 2048, 128);
  decay_ip<<<16384, blk, 0, stream>>>(dec, alog, dtb, 4194304);

  gemm_mfma<float><<<dim3(1, 16), blk, 0, stream>>>(x, bw, beta, M, 64, 2048);
  sigmoid_ip<<<512, blk, 0, stream>>>(beta, 131072);

  gemm_mfma<float><<<dim3(1, 16), blk, 0, stream>>>(x, g1w, g1t, M, 128, 2048);
  gemm_mfma<unsigned short><<<dim3(16, 16), blk, 0, stream>>>(g1t, g2w, gate, M, 2048, 128);

  // ---- l2 norms (in-place bf16) ----
  l2norm_bf16<<<8192, blk, 0, stream>>>(Qc, 32768, 0.08838834764831845f);
  l2norm_bf16<<<32768, blk, 0, stream>>>(Kc, 131072, 1.0f);

  // ---- recurrent scan (R9 math + XCD-clustered remap) ----
  scan_kernel6<<<1024, dim3(256), 0, stream>>>(Qc, Kc, Vc, dec, beta, ml, alog, dtb, o);

  // ---- RMS-norm + gate ----
  norm_gate<<<8192, blk, 0, stream>>>(o, gate, g2b, onw, 32768);

  // ---- final projection -> fp32 out ----
  gemm_mfma<float><<<dim3(16, 16), blk, 0, stream>>>(o, ow, out, M, 2048, 2048);
}

// Round 6
// 1759.619 us; speedup vs baseline: 1.4376x; 1.1681x over previous
//
#include <hip/hip_runtime.h>
#include <hip/hip_bf16.h>
#include <math.h>

// B=2 T=1024 HID=2048 H=16 D=128 DV=128 R=4 CONV=4
// R13 = R12 resubmit (infra failure, no counters) with hedged staging:
// gemm_bf16 uses global_load_lds dwordx4 when the builtin exists, else
// per-lane uint4 load + ds_write_b128 to the IDENTICAL swizzled layout.
// Big GEMMs (K/V/Q/o_proj): pure-bf16, 128x128 tile, BK=64, XOR-swizzled
// 16B groups (g^row&7) on stage+read (rule #21), zero staging VALU.
// Small GEMMs keep R11 f32 path. Scan/conv/norms byte-identical R11
// (scan_kernel6 = R9 math + XCD remap, 858us validated).

typedef unsigned short ushort_t;
typedef __attribute__((ext_vector_type(8))) short bf16x8;
typedef __attribute__((ext_vector_type(4))) float f32x4;
typedef __attribute__((ext_vector_type(8))) unsigned short u16x8;

__device__ __forceinline__ unsigned short f2bf(float f) {
  unsigned u = __float_as_uint(f);
  unsigned r = (u + 0x7FFFu + ((u >> 16) & 1u)) >> 16;  // RNE
  return (unsigned short)r;
}
// HW packed fp32->bf16 (RNE), lo in [15:0], hi in [31:16].
__device__ __forceinline__ unsigned f2bf_pk(float lo, float hi) {
  unsigned r;
  asm("v_cvt_pk_bf16_f32 %0, %1, %2" : "=v"(r) : "v"(lo), "v"(hi));
  return r;
}
__device__ __forceinline__ float bf2f(unsigned short u) {
  return __uint_as_float(((unsigned)u) << 16);
}
__device__ __forceinline__ float sigmoidf(float x) { return 1.f / (1.f + expf(-x)); }
__device__ __forceinline__ float softplusf(float x) {
  return (x > 20.f) ? x : log1pf(expf(x));
}
__device__ __forceinline__ void store1(float* p, float v) { *p = v; }
__device__ __forceinline__ void store1(unsigned short* p, float v) {
  *p = (unsigned short)f2bf_pk(v, v);
}

// Stage 1KB (64 lanes x 16B): per-lane global src, wave-uniform LDS base.
// Primary: async global->LDS (HW adds lane*16 to dest). Fallback: per-lane
// load + ds_write to base + lane*16 (identical layout, sync).
#if __has_builtin(__builtin_amdgcn_global_load_lds)
__device__ __forceinline__ void gload16(const void* g, void* lds, int lane) {
  (void)lane;
  __builtin_amdgcn_global_load_lds(
      (const __attribute__((address_space(1))) unsigned int*)g,
      (__attribute__((address_space(3))) unsigned int*)lds, 16, 0, 0);
}
#else
__device__ __forceinline__ void gload16(const void* g, void* lds, int lane) {
  uint4 v = *(const uint4*)g;
  *(uint4*)((char*)lds + lane * 16) = v;
}
#endif

// ---------------------------------------------------------------------------
// f32 -> bf16 convert, x8 per thread.
// ---------------------------------------------------------------------------
__global__ __launch_bounds__(256) void cvt_bf16_v8(const float* __restrict__ X,
                                                   unsigned short* __restrict__ Y,
                                                   int total8) {
  int i = blockIdx.x * 256 + threadIdx.x;
  if (i >= total8) return;
  const float4* s = (const float4*)(X + (size_t)i * 8);
  float4 a = s[0], b = s[1];
  *(uint4*)(Y + (size_t)i * 8) = make_uint4(f2bf_pk(a.x, a.y), f2bf_pk(a.z, a.w),
                                            f2bf_pk(b.x, b.y), f2bf_pk(b.z, b.w));
}

// ---------------------------------------------------------------------------
// bf16 NT GEMM: Y[m,n] = sum_k A[m,k]*B[n,k]; A (M,K), B (N,K) bf16 row-major.
// 128x128 tile, BK=64, 256 thr (4 waves 2x2, 4x4 16x16x32 frags/wave).
// LDS linear [128][64] bf16 (128B rows), 16B groups XOR-swizzled:
//   storage_g = logical_g ^ (row & 7)
// Stage: wave w rows [w*32,w*32+32), 4 issues x 1KB; lane l -> storage row
// w*32+r*8+(l>>3), storage g = l&7, so the GLOBAL source is pre-swizzled:
// logical g = (l&7) ^ ((l>>3)&7).
// Read: ds_read_b128 at row*128B + ((kk*4+quad)^(row&7))*16B (2-way, free).
// Requires M%128==0, N%128==0, K%64==0.
// ---------------------------------------------------------------------------
template <typename OutT>
__global__ __launch_bounds__(256) void gemm_bf16(const unsigned short* __restrict__ A,
                                                 const unsigned short* __restrict__ B,
                                                 OutT* __restrict__ Y,
                                                 int M, int N, int K) {
  __shared__ __attribute__((aligned(16))) unsigned short As[128 * 64];
  __shared__ __attribute__((aligned(16))) unsigned short Bs[128 * 64];
  const int tid = threadIdx.x;
  const int lane = tid & 63;
  const int wave = tid >> 6;
  const int quad = lane >> 4;
  const int l16 = lane & 15;
  const int wm = wave >> 1, wn = wave & 1;
  const int n0 = blockIdx.x * 128;
  const int m0 = blockIdx.y * 128;

  const int srow = lane >> 3;                 // 0..7 within an issue
  const int glog = (lane & 7) ^ (srow & 7);   // pre-swizzled source group
  const unsigned short* Ab = A + (size_t)(m0 + wave * 32 + srow) * K + glog * 8;
  const unsigned short* Bb = B + (size_t)(n0 + wave * 32 + srow) * K + glog * 8;
  unsigned short* AsW = As + wave * 2048;     // 4KB per wave
  unsigned short* BsW = Bs + wave * 2048;

  f32x4 acc[4][4];
#pragma unroll
  for (int i = 0; i < 4; ++i)
#pragma unroll
    for (int j = 0; j < 4; ++j) acc[i][j] = (f32x4){0.f, 0.f, 0.f, 0.f};

  for (int k0 = 0; k0 < K; k0 += 64) {
    __syncthreads();
#pragma unroll
    for (int r = 0; r < 4; ++r) {
      gload16(Ab + (size_t)(r * 8) * K + k0, AsW + r * 512, lane);
      gload16(Bb + (size_t)(r * 8) * K + k0, BsW + r * 512, lane);
    }
    __syncthreads();
#pragma unroll
    for (int kk = 0; kk < 2; ++kk) {
      bf16x8 av[4], bv[4];
#pragma unroll
      for (int i = 0; i < 4; ++i) {
        int row = wm * 64 + i * 16 + l16;
        av[i] = *(const bf16x8*)&As[row * 64 + (((kk * 4 + quad) ^ (row & 7)) * 8)];
      }
#pragma unroll
      for (int j = 0; j < 4; ++j) {
        int row = wn * 64 + j * 16 + l16;
        bv[j] = *(const bf16x8*)&Bs[row * 64 + (((kk * 4 + quad) ^ (row & 7)) * 8)];
      }
#pragma unroll
      for (int i = 0; i < 4; ++i)
#pragma unroll
        for (int j = 0; j < 4; ++j)
          acc[i][j] = __builtin_amdgcn_mfma_f32_16x16x32_bf16(av[i], bv[j], acc[i][j], 0, 0, 0);
    }
  }

  // epilogue: D[row=quad*4+reg][col=l16] per 16x16 tile
#pragma unroll
  for (int i = 0; i < 4; ++i)
#pragma unroll
    for (int j = 0; j < 4; ++j) {
      int rr = m0 + wm * 64 + i * 16 + quad * 4;
      int cc = n0 + wn * 64 + j * 16 + l16;
#pragma unroll
      for (int r = 0; r < 4; ++r)
        store1(Y + (size_t)(rr + r) * N + cc, acc[i][j][r]);
    }
}

// ---------------------------------------------------------------------------
// MFMA GEMM (NT) with f32 inputs — R11-validated; kept for the small GEMMs.
// ---------------------------------------------------------------------------
template <typename OutT>
__global__ __launch_bounds__(256) void gemm_mfma(const float* __restrict__ A,
                                                 const float* __restrict__ B,
                                                 OutT* __restrict__ Y,
                                                 int M, int N, int K) {
  __shared__ __attribute__((aligned(16))) unsigned short As[128 * 40];
  __shared__ __attribute__((aligned(16))) unsigned short Bs[128 * 40];
  const int tid = threadIdx.x;
  const int lane = tid & 63;
  const int wave = tid >> 6;
  const int quad = lane >> 4;
  const int l16 = lane & 15;
  const int wm = wave >> 1;   // 0..1
  const int wn = wave & 1;    // 0..1
  const int n0 = blockIdx.x * 128;
  const int m0 = blockIdx.y * 128;

  f32x4 acc[4][4];
#pragma unroll
  for (int i = 0; i < 4; ++i)
#pragma unroll
    for (int j = 0; j < 4; ++j) acc[i][j] = (f32x4){0.f, 0.f, 0.f, 0.f};

  for (int k0 = 0; k0 < K; k0 += 32) {
    __syncthreads();
#pragma unroll
    for (int u = tid; u < 512; u += 256) {
      int m = u >> 2, c = u & 3;
      const float* src = A + (size_t)(m0 + m) * K + k0 + c * 8;
      float4 a0 = *(const float4*)(src);
      float4 a1 = *(const float4*)(src + 4);
      *(uint2*)&As[m * 40 + c * 8] =
          make_uint2(f2bf_pk(a0.x, a0.y), f2bf_pk(a0.z, a0.w));
      *(uint2*)&As[m * 40 + c * 8 + 4] =
          make_uint2(f2bf_pk(a1.x, a1.y), f2bf_pk(a1.z, a1.w));
    }
#pragma unroll
    for (int u = tid; u < 512; u += 256) {
      int n = u >> 2, c = u & 3;
      float4 b0 = make_float4(0.f, 0.f, 0.f, 0.f);
      float4 b1 = b0;
      if (n0 + n < N) {
        const float* src = B + (size_t)(n0 + n) * K + k0 + c * 8;
        b0 = *(const float4*)(src);
        b1 = *(const float4*)(src + 4);
      }
      *(uint2*)&Bs[n * 40 + c * 8] =
          make_uint2(f2bf_pk(b0.x, b0.y), f2bf_pk(b0.z, b0.w));
      *(uint2*)&Bs[n * 40 + c * 8 + 4] =
          make_uint2(f2bf_pk(b1.x, b1.y), f2bf_pk(b1.z, b1.w));
    }
    __syncthreads();

    bf16x8 av[4], bv[4];
#pragma unroll
    for (int i = 0; i < 4; ++i)
      av[i] = *(const bf16x8*)&As[(wm * 64 + i * 16 + l16) * 40 + quad * 8];
#pragma unroll
    for (int j = 0; j < 4; ++j)
      bv[j] = *(const bf16x8*)&Bs[(wn * 64 + j * 16 + l16) * 40 + quad * 8];
#pragma unroll
    for (int i = 0; i < 4; ++i)
#pragma unroll
      for (int j = 0; j < 4; ++j)
        acc[i][j] = __builtin_amdgcn_mfma_f32_16x16x32_bf16(av[i], bv[j], acc[i][j], 0, 0, 0);
  }

#pragma unroll
  for (int i = 0; i < 4; ++i)
#pragma unroll
    for (int j = 0; j < 4; ++j) {
      int rr = m0 + wm * 64 + i * 16 + quad * 4;
      int cc = n0 + wn * 64 + j * 16 + l16;
      if (cc < N) {
#pragma unroll
        for (int r = 0; r < 4; ++r)
          store1(Y + (size_t)(rr + r) * N + cc, acc[i][j][r]);
      }
    }
}

// ---------------------------------------------------------------------------
// Depthwise causal conv (K=4) + silu — vectorized x8 (ushort8), cvt_pk out.
// ---------------------------------------------------------------------------
__global__ __launch_bounds__(256) void conv_silu_v8(const unsigned short* __restrict__ X,
                                                    const float* __restrict__ Wc,
                                                    unsigned short* __restrict__ Y,
                                                    int C, int total8) {
  int i8 = blockIdx.x * 256 + threadIdx.x;
  if (i8 >= total8) return;
  int idx = i8 * 8;
  int c = idx % C;
  int m = idx / C;
  int t = m & 1023;
  u16x8 x0 = *(const u16x8*)(X + idx);
  u16x8 x1 = (u16x8)(unsigned short)0;
  u16x8 x2 = x1, x3 = x1;
  if (t >= 1) x1 = *(const u16x8*)(X + idx - C);
  if (t >= 2) x2 = *(const u16x8*)(X + idx - 2 * C);
  if (t >= 3) x3 = *(const u16x8*)(X + idx - 3 * C);
  float r[8];
#pragma unroll
  for (int e = 0; e < 8; ++e) {
    float4 w4 = *(const float4*)(Wc + (size_t)(c + e) * 4);
    float acc = w4.w * bf2f(x0[e]);
    acc = fmaf(w4.z, bf2f(x1[e]), acc);
    acc = fmaf(w4.y, bf2f(x2[e]), acc);
    acc = fmaf(w4.x, bf2f(x3[e]), acc);
    r[e] = acc * sigmoidf(acc);
  }
  *(uint4*)(Y + idx) = make_uint4(f2bf_pk(r[0], r[1]), f2bf_pk(r[2], r[3]),
                                  f2bf_pk(r[4], r[5]), f2bf_pk(r[6], r[7]));
}

// ---------------------------------------------------------------------------
// l2norm rows of 128 (bf16, in-place) — R6-validated.
// ---------------------------------------------------------------------------
__global__ __launch_bounds__(256) void l2norm_bf16(unsigned short* __restrict__ X,
                                                   int rows, float post) {
  int row = blockIdx.x * 4 + (threadIdx.x >> 6);
  int lane = threadIdx.x & 63;
  if (row >= rows) return;
  unsigned short* p = X + (size_t)row * 128;
  float a = bf2f(p[lane]), b = bf2f(p[lane + 64]);
  float ss = fmaf(a, a, b * b);
#pragma unroll
  for (int m = 32; m; m >>= 1) ss += __shfl_xor(ss, m);
  float sc = rsqrtf(ss + 1e-6f) * post;
  p[lane] = f2bf(a * sc);
  p[lane + 64] = f2bf(b * sc);
}

// ---------------------------------------------------------------------------
// decay in-place (R6-validated).
// ---------------------------------------------------------------------------
__global__ __launch_bounds__(256) void decay_ip(float* __restrict__ G,
                                                const float* __restrict__ alog,
                                                const float* __restrict__ dtb,
                                                int total) {
  int idx = blockIdx.x * 256 + threadIdx.x;
  if (idx >= total) return;
  int n = idx & 2047;
  float A = expf(alog[n >> 7]);
  float x = G[idx] + dtb[n];
  G[idx] = expf(-A * softplusf(x));
}

__global__ __launch_bounds__(256) void sigmoid_ip(float* __restrict__ G, int total) {
  int idx = blockIdx.x * 256 + threadIdx.x;
  if (idx < total) G[idx] = sigmoidf(G[idx]);
}

// ---------------------------------------------------------------------------
// Recurrent scan v6 — R11-validated (858us): 1 column/wave, 64 lanes over
// d=128 (2 d/lane), scalar math, all-DPP ladder, XCD-clustered remap.
// ---------------------------------------------------------------------------
template <int CTRL>
__device__ __forceinline__ float dppadd(float x) {
  int y = __builtin_amdgcn_update_dpp(0, __float_as_int(x), CTRL, 0xF, 0xF, true);
  return x + __int_as_float(y);
}
__device__ __forceinline__ float red64_l63(float x) {
  x = dppadd<0xB1>(x);
  x = dppadd<0x4E>(x);
  x = dppadd<0x141>(x);
  x = dppadd<0x140>(x);
  x = dppadd<0x142>(x);
  x = dppadd<0x143>(x);
  return x;  // lane 63 holds the 64-lane total
}
__device__ __forceinline__ float red64(float x) {
  return __int_as_float(__builtin_amdgcn_readlane(__float_as_int(red64_l63(x)), 63));
}

struct Pref {
  ushort2 k[4];        // k[j] at d0, d0+1
  ushort2 q;
  float2 d;
  float4 beta;
  unsigned short v[4]; // v[j] at column col (wave-uniform)
};

__global__ __launch_bounds__(256) void scan_kernel6(
    const unsigned short* __restrict__ Qn, const unsigned short* __restrict__ Kn,
    const unsigned short* __restrict__ Vb, const float* __restrict__ Dec,
    const float* __restrict__ BetaS, const float* __restrict__ ml,
    const float* __restrict__ alog, const float* __restrict__ dtb,
    float* __restrict__ O) {
  const int orig = blockIdx.x;       // 0..1023
  const int xcd = orig & 7;
  const int rr = orig >> 3;          // 0..127
  const int bh = xcd * 4 + (rr & 3); // 0..31
  const int cq = rr >> 2;            // 0..31
  const int h = bh & 15;
  const int b = bh >> 4;
  const int wave = threadIdx.x >> 6; // 0..3 -> column within group
  const int lane = threadIdx.x & 63;
  const int col = cq * 4 + wave;
  const int d0 = lane * 2;

  const float A = expf(alog[h]);
  const float df0 = expf(-A * softplusf(-10000.f + dtb[h * 128 + d0]));
  const float df1 = expf(-A * softplusf(-10000.f + dtb[h * 128 + d0 + 1]));

  float wj[4];
  {
    float l0 = ml[h * 4 + 0], l1 = ml[h * 4 + 1];
    float l2 = ml[h * 4 + 2], l3 = ml[h * 4 + 3];
    float mx = fmaxf(fmaxf(l0, l1), fmaxf(l2, l3));
    float e0 = expf(l0 - mx), e1 = expf(l1 - mx);
    float e2 = expf(l2 - mx), e3 = expf(l3 - mx);
    float inv = 1.f / (e0 + e1 + e2 + e3);
    wj[0] = e0 * inv; wj[1] = e1 * inv; wj[2] = e2 * inv; wj[3] = e3 * inv;
  }

  float S0 = 0.f, S1 = 0.f;

  auto LD = [&](int t, Pref& P) {
    const size_t base = ((size_t)(b * 1024 + t) * 16 + h);
    const unsigned short* kp = Kn + base * 512 + d0;
    const unsigned short* vp = Vb + base * 512 + col;
#pragma unroll
    for (int j = 0; j < 4; ++j) {
      P.k[j] = *(const ushort2*)(kp + j * 128);
      P.v[j] = vp[j * 128];
    }
    P.q = *(const ushort2*)(Qn + base * 128 + d0);
    P.d = *(const float2*)(Dec + base * 128 + d0);
    P.beta = *(const float4*)(BetaS + base * 4);
  };

  auto STEP = [&](const Pref& P, int t) {
    const float qf0 = bf2f(P.q.x), qf1 = bf2f(P.q.y);
    float o_acc = 0.f;
    const float bc[4] = {P.beta.x, P.beta.y, P.beta.z, P.beta.w};
#pragma unroll
    for (int j = 0; j < 4; ++j) {
      const float kf0 = bf2f(P.k[j].x), kf1 = bf2f(P.k[j].y);
      const float dd0 = (j == 0) ? P.d.x : df0;
      const float dd1 = (j == 0) ? P.d.y : df1;
      S0 *= dd0;
      S1 *= dd1;
      float u = red64(fmaf(kf0, S0, kf1 * S1));
      float cc = bc[j] * (bf2f(P.v[j]) - u);
      S0 = fmaf(cc, kf0, S0);
      S1 = fmaf(cc, kf1, S1);
      o_acc = fmaf(wj[j], fmaf(qf0, S0, qf1 * S1), o_acc);
    }
    o_acc = red64_l63(o_acc);
    if (lane == 63) {
      const size_t base = ((size_t)(b * 1024 + t) * 16 + h);
      O[base * 128 + col] = o_acc;
    }
  };

  Pref P0, P1;
  LD(0, P0);
  for (int t = 0; t < 1024; t += 2) {
    LD(t + 1, P1);
    STEP(P0, t);
    if (t + 2 < 1024) LD(t + 2, P0);
    STEP(P1, t + 1);
  }
}

// ---------------------------------------------------------------------------
// RMS-norm * o_norm_w * sigmoid(gate + g2_b), in-place on O(f32) — R6-validated.
// ---------------------------------------------------------------------------
__global__ __launch_bounds__(256) void norm_gate(float* __restrict__ O,
                                                 const unsigned short* __restrict__ G,
                                                 const float* __restrict__ g2b,
                                                 const float* __restrict__ onw,
                                                 int rows) {
  int row = blockIdx.x * 4 + (threadIdx.x >> 6);
  int lane = threadIdx.x & 63;
  if (row >= rows) return;
  float* p = O + (size_t)row * 128;
  int m = row >> 4, h = row & 15;
  const unsigned short* gp = G + (size_t)m * 2048 + h * 128;
  const float* gb = g2b + h * 128;
  float a = p[lane], bv = p[lane + 64];
  float ss = fmaf(a, a, bv * bv);
#pragma unroll
  for (int k = 32; k; k >>= 1) ss += __shfl_xor(ss, k);
  float sc = rsqrtf(ss * (1.f / 128.f) + 1e-5f);
  float ga = sigmoidf(bf2f(gp[lane]) + gb[lane]);
  float gbv = sigmoidf(bf2f(gp[lane + 64]) + gb[lane + 64]);
  p[lane] = a * sc * onw[lane] * ga;
  p[lane + 64] = bv * sc * onw[lane + 64] * gbv;
}

// ---------------------------------------------------------------------------
extern "C" void kernel_launch(void* const* d_in, const int* in_sizes, int n_in,
                              void* d_out, int out_size, void* d_ws, size_t ws_size,
                              hipStream_t stream) {
  const float* x    = (const float*)d_in[0];
  const float* qw   = (const float*)d_in[1];
  const float* kw   = (const float*)d_in[2];
  const float* vw   = (const float*)d_in[3];
  const float* qcw  = (const float*)d_in[4];
  const float* kcw  = (const float*)d_in[5];
  const float* vcw  = (const float*)d_in[6];
  const float* f1w  = (const float*)d_in[7];
  const float* f2w  = (const float*)d_in[8];
  const float* bw   = (const float*)d_in[9];
  const float* ml   = (const float*)d_in[10];
  const float* alog = (const float*)d_in[11];
  const float* dtb  = (const float*)d_in[12];
  const float* g1w  = (const float*)d_in[13];
  const float* g2w  = (const float*)d_in[14];
  const float* g2b  = (const float*)d_in[15];
  const float* onw  = (const float*)d_in[16];
  const float* ow   = (const float*)d_in[17];
  float* out = (float*)d_out;  // fp32 output

  // workspace carve — peak 120 MiB.
  // [0,32M)    P (phase-1 GEMM staging) / phase-2: dec[0,16M) gate[16,24M)
  //            beta[24,24.5M) g1t[24.5,25.5M) / post-scan: owbf[0,8M) obf[8,16M)
  // [32M,64M)  Kc
  // [64M,96M)  kwbf -> vwbf -> Vc   (each dead before next writer)
  // [96M,104M) Qc
  // [104M,120M) xbf[104,112M) qwbf[112,120M) -> o (scan output, f32 16M)
  char* w8 = (char*)d_ws;
  unsigned short* P    = (unsigned short*)(w8);               // [0, 32M)
  float*          dec  = (float*)(w8);                        // [0, 16M)
  unsigned short* gate = (unsigned short*)(w8 + 16777216);    // 8 MB
  float*          beta = (float*)(w8 + 25165824);             // 512 KB
  float*          g1t  = (float*)(w8 + 25690112);             // 1 MB
  unsigned short* Kc   = (unsigned short*)(w8 + 33554432);    // 32 MB
  unsigned short* Vc   = (unsigned short*)(w8 + 67108864);    // 32 MB
  unsigned short* wbig = (unsigned short*)(w8 + 67108864);    // kwbf/vwbf (32 MB)
  unsigned short* Qc   = (unsigned short*)(w8 + 100663296);   // 8 MB
  unsigned short* xbf  = (unsigned short*)(w8 + 109051904);   // 8 MB
  unsigned short* qwbf = (unsigned short*)(w8 + 117440512);   // 8 MB (ends 120MiB)
  float*          o    = (float*)(w8 + 109051904);            // 16 MB (scan out)
  unsigned short* owbf = (unsigned short*)(w8);               // 8 MB (post-scan)
  unsigned short* obf  = (unsigned short*)(w8 + 8388608);     // 8 MB (post-scan)
  (void)ws_size;

  const int M = 2048;
  dim3 blk(256);

  // ---- convert x once (used by K/V/Q big GEMMs) ----
  cvt_bf16_v8<<<2048, blk, 0, stream>>>(x, xbf, 524288);

  // ---- phase 1: big projections (bf16 MFMA + gload_lds) + conv ----
  cvt_bf16_v8<<<8192, blk, 0, stream>>>(kw, wbig, 2097152);
  gemm_bf16<unsigned short><<<dim3(64, 16), blk, 0, stream>>>(xbf, wbig, P, M, 8192, 2048);
  conv_silu_v8<<<8192, blk, 0, stream>>>(P, kcw, Kc, 8192, 2097152);
  cvt_bf16_v8<<<8192, blk, 0, stream>>>(vw, wbig, 2097152);
  gemm_bf16<unsigned short><<<dim3(64, 16), blk, 0, stream>>>(xbf, wbig, P, M, 8192, 2048);
  conv_silu_v8<<<8192, blk, 0, stream>>>(P, vcw, Vc, 8192, 2097152);
  cvt_bf16_v8<<<2048, blk, 0, stream>>>(qw, qwbf, 524288);
  gemm_bf16<unsigned short><<<dim3(16, 16), blk, 0, stream>>>(xbf, qwbf, P, M, 2048, 2048);
  conv_silu_v8<<<2048, blk, 0, stream>>>(P, qcw, Qc, 2048, 524288);

  // ---- phase 2: small projections (f32 path; P region now dead) ----
  gemm_mfma<float><<<dim3(1, 16), blk, 0, stream>>>(x, f1w, g1t, M, 128, 2048);
  gemm_mfma<float><<<dim3(16, 16), blk, 0, stream>>>(g1t, f2w, dec, M, 2048, 128);
  decay_ip<<<16384, blk, 0, stream>>>(dec, alog, dtb, 4194304);

  gemm_mfma<float><<<dim3(1, 16), blk, 0, stream>>>(x, bw, beta, M, 64, 2048);
  sigmoid_ip<<<512, blk, 0, stream>>>(beta, 131072);

  gemm_mfma<float><<<dim3(1, 16), blk, 0, stream>>>(x, g1w, g1t, M, 128, 2048);
  gemm_mfma<unsigned short><<<dim3(16, 16), blk, 0, stream>>>(g1t, g2w, gate, M, 2048, 128);

  // ---- l2 norms (in-place bf16) ----
  l2norm_bf16<<<8192, blk, 0, stream>>>(Qc, 32768, 0.08838834764831845f);
  l2norm_bf16<<<32768, blk, 0, stream>>>(Kc, 131072, 1.0f);

  // ---- recurrent scan (R11-validated) ----
  scan_kernel6<<<1024, dim3(256), 0, stream>>>(Qc, Kc, Vc, dec, beta, ml, alog, dtb, o);

  // ---- RMS-norm + gate ----
  norm_gate<<<8192, blk, 0, stream>>>(o, gate, g2b, onw, 32768);

  // ---- final projection (bf16 path) -> fp32 out ----
  cvt_bf16_v8<<<2048, blk, 0, stream>>>(o, obf, 524288);
  cvt_bf16_v8<<<2048, blk, 0, stream>>>(ow, owbf, 524288);
  gemm_bf16<float><<<dim3(16, 16), blk, 0, stream>>>(obf, owbf, out, M, 2048, 2048);
}